// Round 1
// baseline (558.344 us; speedup 1.0000x reference)
//
#include <hip/hip_runtime.h>
#include <hip/hip_bf16.h>

#define NTOK 32768   // 8*64*64 tokens
#define CIN 192
#define C3 576
#define HEADS 8
#define HD 24

// ---------------------------------------------------------------------------
// K1/K5: Y[o,n] = bias[o] + sum_{c<192} W[o,c] * X[c,n]
// tile 64(o) x 128(n), block 256: ty=tid>>5 -> 8 o each, tx=tid&31 -> 4 n (stride 32)
// Wl staged transposed [k][o] with pad 68 (bank-conflict-free, float4-aligned rows)
// ---------------------------------------------------------------------------
__global__ __launch_bounds__(256) void k_gemm_wx(
    const float* __restrict__ X, const float* __restrict__ W,
    const float* __restrict__ bias, float* __restrict__ Y)
{
  const int tid = threadIdx.x;
  const int n0 = blockIdx.x * 128;
  const int o0 = blockIdx.y * 64;
  const int tx = tid & 31;
  const int ty = tid >> 5;
  __shared__ float Wl[16][68];
  __shared__ float Xl[16][128];
  float acc[8][4];
#pragma unroll
  for (int i = 0; i < 8; ++i)
#pragma unroll
    for (int j = 0; j < 4; ++j) acc[i][j] = 0.f;

  for (int k0 = 0; k0 < CIN; k0 += 16) {
    __syncthreads();
#pragma unroll
    for (int i = 0; i < 4; ++i) {              // 64*16 = 1024 elems
      int idx = tid + i * 256;
      int oo = idx >> 4, kk = idx & 15;
      Wl[kk][oo] = W[(size_t)(o0 + oo) * CIN + k0 + kk];
    }
#pragma unroll
    for (int i = 0; i < 8; ++i) {              // 16*128 = 2048 elems
      int idx = tid + i * 256;
      int kk = idx >> 7, nn = idx & 127;
      Xl[kk][nn] = X[(size_t)(k0 + kk) * NTOK + n0 + nn];
    }
    __syncthreads();
#pragma unroll
    for (int kk = 0; kk < 16; ++kk) {
      float4 w0 = *reinterpret_cast<const float4*>(&Wl[kk][ty * 8]);
      float4 w1 = *reinterpret_cast<const float4*>(&Wl[kk][ty * 8 + 4]);
      float wr[8] = {w0.x, w0.y, w0.z, w0.w, w1.x, w1.y, w1.z, w1.w};
      float xr[4];
#pragma unroll
      for (int j = 0; j < 4; ++j) xr[j] = Xl[kk][tx + 32 * j];
#pragma unroll
      for (int i = 0; i < 8; ++i)
#pragma unroll
        for (int j = 0; j < 4; ++j) acc[i][j] += wr[i] * xr[j];
    }
  }
#pragma unroll
  for (int i = 0; i < 8; ++i) {
    int o = o0 + ty * 8 + i;
    float bv = bias[o];
#pragma unroll
    for (int j = 0; j < 4; ++j)
      Y[(size_t)o * NTOK + n0 + tx + 32 * j] = acc[i][j] + bv;
  }
}

// ---------------------------------------------------------------------------
// K2: depthwise 3x3x3, pad 1. One block = (channel, 16-row h-slab), full t and w.
// ---------------------------------------------------------------------------
__global__ __launch_bounds__(256) void k_dwconv(
    const float* __restrict__ in,   // [CH_chunk][8][64][64] chunk-local
    const float* __restrict__ wdw,  // [576][27]
    const float* __restrict__ bdw,  // [576]
    float* __restrict__ out,        // [576][8][64][64] batch-local
    int c_start)
{
  const int tid = threadIdx.x;
  const int chl = blockIdx.y;
  const int ch = c_start + chl;
  const int h0 = blockIdx.x * 16;
  __shared__ float s[8][18][66];
  const float* inch = in + (size_t)chl * NTOK;

  for (int i = tid; i < 8 * 18 * 66; i += 256) {
    int t = i / (18 * 66);
    int rem = i % (18 * 66);
    int r = rem / 66;
    int cc = rem % 66;
    int h = h0 + r - 1;
    int w = cc - 1;
    float v = 0.f;
    if (h >= 0 && h < 64 && w >= 0 && w < 64)
      v = inch[t * 4096 + h * 64 + w];
    s[t][r][cc] = v;
  }
  float wr[27];
#pragma unroll
  for (int i = 0; i < 27; ++i) wr[i] = wdw[ch * 27 + i];
  const float bias = bdw[ch];
  __syncthreads();

  const int wloc = tid & 63;
  const int hs = tid >> 6;  // 0..3
  float* outch = out + (size_t)ch * NTOK;
  for (int hi = 0; hi < 4; ++hi) {
    const int hl = hs * 4 + hi;  // 0..15
#pragma unroll
    for (int t = 0; t < 8; ++t) {
      float a = bias;
#pragma unroll
      for (int dt = -1; dt <= 1; ++dt) {
        int tt = t + dt;
        if (tt < 0 || tt > 7) continue;
#pragma unroll
        for (int dh = 0; dh < 3; ++dh)
#pragma unroll
          for (int dw = 0; dw < 3; ++dw)
            a += wr[(dt + 1) * 9 + dh * 3 + dw] * s[tt][hl + dh][wloc + dw];
      }
      outch[t * 4096 + (h0 + hl) * 64 + wloc] = a;
    }
  }
}

// ---------------------------------------------------------------------------
// K3: Gram S[c,d] = sum_n q[c,n]k[d,n] and sumsq of each q/k row, per head.
// grid (32 n-chunks of 1024, 8 heads); fp32 atomics into zeroed accumulators.
// ---------------------------------------------------------------------------
__global__ __launch_bounds__(256) void k_gram(
    const float* __restrict__ post,  // batch-local [576][NTOK]
    float* __restrict__ Sb,          // [8][24*24]
    float* __restrict__ nqb,         // [8][24]
    float* __restrict__ nkb)         // [8][24]
{
  const int tid = threadIdx.x;
  const int h = blockIdx.y;
  const int n0 = blockIdx.x * 1024;
  const float* q = post + (size_t)(h * HD) * NTOK;
  const float* k = post + (size_t)(192 + h * HD) * NTOK;
  __shared__ float qs[32][65];
  __shared__ float ks[32][65];

  // zero the pad rows (24..31) once
  for (int i = tid; i < 8 * 64; i += 256) {
    int r = 24 + (i >> 6);
    qs[r][i & 63] = 0.f;
    ks[r][i & 63] = 0.f;
  }

  const int ty = tid >> 4;     // 0..15 -> c0 = 2*ty
  const int tx = tid & 15;     // 0..15 -> d0 = 2*tx
  float a00 = 0, a01 = 0, a10 = 0, a11 = 0;
  float sq = 0;

  for (int sub = 0; sub < 16; ++sub) {
    __syncthreads();
    for (int i = tid; i < 24 * 64; i += 256) {
      int r = i >> 6, cc = i & 63;
      int col = n0 + (sub << 6) + cc;
      qs[r][cc] = q[(size_t)r * NTOK + col];
      ks[r][cc] = k[(size_t)r * NTOK + col];
    }
    __syncthreads();
#pragma unroll 8
    for (int j = 0; j < 64; ++j) {
      float q0 = qs[ty * 2][j], q1 = qs[ty * 2 + 1][j];
      float k0 = ks[tx * 2][j], k1 = ks[tx * 2 + 1][j];
      a00 += q0 * k0; a01 += q0 * k1; a10 += q1 * k0; a11 += q1 * k1;
    }
    if (tid < 24) {
#pragma unroll 8
      for (int j = 0; j < 64; ++j) { float v = qs[tid][j]; sq += v * v; }
    } else if (tid < 48) {
#pragma unroll 8
      for (int j = 0; j < 64; ++j) { float v = ks[tid - 24][j]; sq += v * v; }
    }
  }
  const int c0 = ty * 2, d0 = tx * 2;
  if (c0 < 24 && d0 < 24) {
    atomicAdd(&Sb[h * 576 + c0 * 24 + d0], a00);
    atomicAdd(&Sb[h * 576 + c0 * 24 + d0 + 1], a01);
    atomicAdd(&Sb[h * 576 + (c0 + 1) * 24 + d0], a10);
    atomicAdd(&Sb[h * 576 + (c0 + 1) * 24 + d0 + 1], a11);
  }
  if (tid < 24) atomicAdd(&nqb[h * 24 + tid], sq);
  else if (tid < 48) atomicAdd(&nkb[h * 24 + tid - 24], sq);
}

// ---------------------------------------------------------------------------
// K4: attn = softmax(S * temp / (|q||k|)); Wcomb[o][h*24+d] = sum_c projW[o][h*24+c]*attn[c][d]
// one block per head.
// ---------------------------------------------------------------------------
__global__ __launch_bounds__(256) void k_attn_wcomb(
    const float* __restrict__ Sb, const float* __restrict__ nqb,
    const float* __restrict__ nkb, const float* __restrict__ temp,
    const float* __restrict__ projw, float* __restrict__ wcomb)
{
  const int h = blockIdx.x;
  const int tid = threadIdx.x;
  __shared__ float attn[24][25];
  __shared__ float nqs[24], nks[24];
  if (tid < 24) nqs[tid] = fmaxf(sqrtf(nqb[h * 24 + tid]), 1e-12f);
  else if (tid < 48) nks[tid - 24] = fmaxf(sqrtf(nkb[h * 24 + tid - 24]), 1e-12f);
  __syncthreads();
  if (tid < 24) {
    const int c = tid;
    const float tmp = temp[h];
    float row[24];
    float m = -1e30f;
#pragma unroll
    for (int d = 0; d < 24; ++d) {
      float v = Sb[h * 576 + c * 24 + d] / (nqs[c] * nks[d]) * tmp;
      row[d] = v;
      m = fmaxf(m, v);
    }
    float ssum = 0.f;
#pragma unroll
    for (int d = 0; d < 24; ++d) { float e = __expf(row[d] - m); row[d] = e; ssum += e; }
    const float inv = 1.f / ssum;
#pragma unroll
    for (int d = 0; d < 24; ++d) attn[c][d] = row[d] * inv;
  }
  __syncthreads();
  for (int e = tid; e < 192 * 24; e += 256) {
    int o = e / 24, d = e % 24;
    float a = 0.f;
#pragma unroll
    for (int c = 0; c < 24; ++c) a += projw[o * 192 + h * 24 + c] * attn[c][d];
    wcomb[o * 192 + h * 24 + d] = a;
  }
}

// ---------------------------------------------------------------------------
extern "C" void kernel_launch(void* const* d_in, const int* in_sizes, int n_in,
                              void* d_out, int out_size, void* d_ws, size_t ws_size,
                              hipStream_t stream) {
  const float* x      = (const float*)d_in[0];
  const float* qkv_w  = (const float*)d_in[1];
  const float* qkv_b  = (const float*)d_in[2];
  const float* dw_w   = (const float*)d_in[3];
  const float* dw_b   = (const float*)d_in[4];
  const float* temp   = (const float*)d_in[5];
  const float* proj_w = (const float*)d_in[6];
  const float* proj_b = (const float*)d_in[7];
  float* out = (float*)d_out;

  char* ws = (char*)d_ws;
  size_t off = 0;
  float* post = (float*)(ws + off); off += (size_t)C3 * NTOK * sizeof(float);   // 75.5 MB
  float* Sb0  = (float*)(ws + off);                  // [2][8][576]
  float* nqb0 = Sb0 + 2 * HEADS * HD * HD;           // [2][8][24]
  float* nkb0 = nqb0 + 2 * HEADS * HD;               // [2][8][24]
  size_t stotal = (size_t)(2 * HEADS * HD * HD + 4 * HEADS * HD) * sizeof(float);
  off += stotal;
  float* wcomb = (float*)(ws + off); off += (size_t)CIN * CIN * sizeof(float);
  off = (off + 255) & ~(size_t)255;
  float* pre = (float*)(ws + off);

  size_t remain = (ws_size > off) ? ws_size - off : 0;
  int CH = (int)(remain / ((size_t)NTOK * sizeof(float)));
  if (CH > C3) CH = C3;
  CH = (CH / 64) * 64;
  if (CH < 64) CH = 64;   // below this we cannot fit; best effort

  hipMemsetAsync(Sb0, 0, stotal, stream);

  for (int b = 0; b < 2; ++b) {
    const float* xb = x + (size_t)b * CIN * NTOK;
    for (int cs = 0; cs < C3; cs += CH) {
      int cc = C3 - cs; if (cc > CH) cc = CH;
      dim3 g1(NTOK / 128, cc / 64);
      k_gemm_wx<<<g1, 256, 0, stream>>>(xb, qkv_w + (size_t)cs * CIN, qkv_b + cs, pre);
      dim3 g2(4, cc);
      k_dwconv<<<g2, 256, 0, stream>>>(pre, dw_w, dw_b, post, cs);
    }
    float* Sb  = Sb0 + (size_t)b * HEADS * HD * HD;
    float* nqb = nqb0 + (size_t)b * HEADS * HD;
    float* nkb = nkb0 + (size_t)b * HEADS * HD;
    dim3 g3(32, HEADS);
    k_gram<<<g3, 256, 0, stream>>>(post, Sb, nqb, nkb);
    k_attn_wcomb<<<HEADS, 256, 0, stream>>>(Sb, nqb, nkb, temp, proj_w, wcomb);
    dim3 g5(NTOK / 128, 3);
    k_gemm_wx<<<g5, 256, 0, stream>>>(post + (size_t)384 * NTOK, wcomb, proj_b,
                                      out + (size_t)b * CIN * NTOK);
  }
}

// Round 2
// 376.781 us; speedup vs baseline: 1.4819x; 1.4819x over previous
//
#include <hip/hip_runtime.h>

#define NTOK 32768   // 8*64*64 tokens
#define CIN 192
#define C3 576
#define HEADS 8
#define HD 24

typedef __attribute__((ext_vector_type(8))) short bf16x8;
typedef __attribute__((ext_vector_type(16))) float f32x16;

__device__ __forceinline__ float bf2f(unsigned int u) {
  union { unsigned int i; float f; } x; x.i = u << 16; return x.f;
}
__device__ __forceinline__ unsigned short f2bf(float f) {
  union { float f; unsigned int i; } x; x.f = f;
  unsigned int r = x.i + 0x7fffu + ((x.i >> 16) & 1u);
  return (unsigned short)(r >> 16);
}

// ---------------------------------------------------------------------------
// MFMA GEMM: Y[o,n] = bias[o] + sum_{c<192} W[o,c] * X[c,n]
// block 256 = 4 waves; tile 64(o) x 64(n); full K=192 staged once.
// Each wave computes one 32x32 quadrant via 12x mfma_f32_32x32x16_bf16.
// Xs staged transposed [n][c] (c-contiguous for B-frag), rows padded to 200.
// Epilogue repacks through LDS (aliasing Wl) for coalesced stores.
// XBF: X is bf16 (ushort) input; else fp32 (converted). OUTF32: write fp32.
// ---------------------------------------------------------------------------
template<int XBF, int OUTF32>
__global__ __launch_bounds__(256) void k_gemm_mfma(
    const void* __restrict__ Xv, const float* __restrict__ W,
    const float* __restrict__ bias, void* __restrict__ Yv)
{
  __shared__ __align__(16) unsigned short Wl[64][200];
  __shared__ __align__(16) unsigned short Xs[64][200];
  const int tid = threadIdx.x;
  const int n0 = blockIdx.x * 64;
  const int o0 = blockIdx.y * 64;

  { // stage W (fp32 -> bf16): 64 rows x 192
    const int oo = tid >> 2;
    const int q0 = tid & 3;
#pragma unroll
    for (int j = 0; j < 12; ++j) {
      const int c = (j * 4 + q0) * 4;
      float4 v = *(const float4*)&W[(size_t)(o0 + oo) * CIN + c];
      Wl[oo][c]     = f2bf(v.x);
      Wl[oo][c + 1] = f2bf(v.y);
      Wl[oo][c + 2] = f2bf(v.z);
      Wl[oo][c + 3] = f2bf(v.w);
    }
  }
  { // stage X transposed -> Xs[n][c]
    const int nn = (tid & 31) * 2;
    const int cg = tid >> 5;           // 0..7
    if (XBF) {
      const unsigned short* X = (const unsigned short*)Xv;
#pragma unroll
      for (int j = 0; j < 24; ++j) {
        const int c = j * 8 + cg;
        unsigned int w = *(const unsigned int*)&X[(size_t)c * NTOK + n0 + nn];
        Xs[nn][c]     = (unsigned short)(w & 0xffffu);
        Xs[nn + 1][c] = (unsigned short)(w >> 16);
      }
    } else {
      const float* X = (const float*)Xv;
#pragma unroll
      for (int j = 0; j < 24; ++j) {
        const int c = j * 8 + cg;
        float2 v = *(const float2*)&X[(size_t)c * NTOK + n0 + nn];
        Xs[nn][c]     = f2bf(v.x);
        Xs[nn + 1][c] = f2bf(v.y);
      }
    }
  }
  __syncthreads();

  const int lane = tid & 63;
  const int wv = tid >> 6;
  const int o_w = (wv >> 1) * 32;
  const int n_w = (wv & 1) * 32;
  const int r32 = lane & 31;
  const int hi = lane >> 5;

  f32x16 acc;
#pragma unroll
  for (int i = 0; i < 16; ++i) acc[i] = 0.f;

  const unsigned short* wp = &Wl[o_w + r32][hi * 8];
  const unsigned short* xp = &Xs[n_w + r32][hi * 8];
#pragma unroll
  for (int kk = 0; kk < 12; ++kk) {
    bf16x8 a = *(const bf16x8*)(wp + kk * 16);
    bf16x8 b = *(const bf16x8*)(xp + kk * 16);
    acc = __builtin_amdgcn_mfma_f32_32x32x16_bf16(a, b, acc, 0, 0, 0);
  }
  __syncthreads();

  if (OUTF32) {
    float (*Yl)[68] = (float(*)[68])&Wl[0][0];   // 64*68*4 = 17408 B <= 25600 B
#pragma unroll
    for (int r = 0; r < 16; ++r) {
      const int row = o_w + (r & 3) + 8 * (r >> 2) + 4 * hi;
      Yl[row][n_w + r32] = acc[r] + bias[o0 + row];
    }
    __syncthreads();
    float* Y = (float*)Yv;
    const int row = tid >> 2, seg = (tid & 3) * 16;
#pragma unroll
    for (int v = 0; v < 4; ++v) {
      float4 val = *(const float4*)&Yl[row][seg + v * 4];
      *(float4*)&Y[(size_t)(o0 + row) * NTOK + n0 + seg + v * 4] = val;
    }
  } else {
    unsigned short (*Yl)[72] = (unsigned short(*)[72])&Wl[0][0];  // 9216 B
#pragma unroll
    for (int r = 0; r < 16; ++r) {
      const int row = o_w + (r & 3) + 8 * (r >> 2) + 4 * hi;
      Yl[row][n_w + r32] = f2bf(acc[r] + bias[o0 + row]);
    }
    __syncthreads();
    unsigned short* Y = (unsigned short*)Yv;
    const int row = tid >> 2, seg = (tid & 3) * 16;
#pragma unroll
    for (int v = 0; v < 2; ++v) {
      bf16x8 val = *(const bf16x8*)&Yl[row][seg + v * 8];
      *(bf16x8*)&Y[(size_t)(o0 + row) * NTOK + n0 + seg + v * 8] = val;
    }
  }
}

// ---------------------------------------------------------------------------
// K2: depthwise 3x3x3, pad 1, bf16 in/out, fp32 math.
// ---------------------------------------------------------------------------
__global__ __launch_bounds__(256) void k_dwconv(
    const unsigned short* __restrict__ in,   // [CH_chunk][8][64][64] bf16
    const float* __restrict__ wdw,           // [576][27]
    const float* __restrict__ bdw,           // [576]
    unsigned short* __restrict__ out,        // [576][8][64][64] bf16
    int c_start)
{
  const int tid = threadIdx.x;
  const int chl = blockIdx.y;
  const int ch = c_start + chl;
  const int h0 = blockIdx.x * 16;
  __shared__ float s[8][18][66];
  const unsigned short* inch = in + (size_t)chl * NTOK;

  for (int i = tid; i < 8 * 18 * 66; i += 256) {
    int t = i / (18 * 66);
    int rem = i % (18 * 66);
    int r = rem / 66;
    int cc = rem % 66;
    int h = h0 + r - 1;
    int w = cc - 1;
    float v = 0.f;
    if (h >= 0 && h < 64 && w >= 0 && w < 64)
      v = bf2f(inch[t * 4096 + h * 64 + w]);
    s[t][r][cc] = v;
  }
  float wr[27];
#pragma unroll
  for (int i = 0; i < 27; ++i) wr[i] = wdw[ch * 27 + i];
  const float bias = bdw[ch];
  __syncthreads();

  const int wloc = tid & 63;
  const int hs = tid >> 6;  // 0..3
  unsigned short* outch = out + (size_t)ch * NTOK;
  for (int hi = 0; hi < 4; ++hi) {
    const int hl = hs * 4 + hi;  // 0..15
#pragma unroll
    for (int t = 0; t < 8; ++t) {
      float a = bias;
#pragma unroll
      for (int dt = -1; dt <= 1; ++dt) {
        int tt = t + dt;
        if (tt < 0 || tt > 7) continue;
#pragma unroll
        for (int dh = 0; dh < 3; ++dh)
#pragma unroll
          for (int dw = 0; dw < 3; ++dw)
            a += wr[(dt + 1) * 9 + dh * 3 + dw] * s[tt][hl + dh][wloc + dw];
      }
      outch[t * 4096 + (h0 + hl) * 64 + wloc] = f2bf(a);
    }
  }
}

// ---------------------------------------------------------------------------
// K3: Gram S[c,d] = sum_n q[c,n]k[d,n] + row sumsq, per head (bf16 input).
// ---------------------------------------------------------------------------
__global__ __launch_bounds__(256) void k_gram(
    const unsigned short* __restrict__ post,  // batch-local [576][NTOK] bf16
    float* __restrict__ Sb,                   // [8][24*24]
    float* __restrict__ nqb,                  // [8][24]
    float* __restrict__ nkb)                  // [8][24]
{
  const int tid = threadIdx.x;
  const int h = blockIdx.y;
  const int n0 = blockIdx.x * 1024;
  const unsigned short* q = post + (size_t)(h * HD) * NTOK;
  const unsigned short* k = post + (size_t)(192 + h * HD) * NTOK;
  __shared__ float qs[32][65];
  __shared__ float ks[32][65];

  for (int i = tid; i < 8 * 64; i += 256) {
    int r = 24 + (i >> 6);
    qs[r][i & 63] = 0.f;
    ks[r][i & 63] = 0.f;
  }

  const int ty = tid >> 4;
  const int tx = tid & 15;
  float a00 = 0, a01 = 0, a10 = 0, a11 = 0;
  float sq = 0;

  for (int sub = 0; sub < 16; ++sub) {
    __syncthreads();
    for (int i = tid; i < 768; i += 256) {
      int r = i >> 5, cc = (i & 31) * 2;
      int col = n0 + (sub << 6) + cc;
      unsigned int wq = *(const unsigned int*)&q[(size_t)r * NTOK + col];
      unsigned int wk = *(const unsigned int*)&k[(size_t)r * NTOK + col];
      qs[r][cc] = bf2f(wq & 0xffffu); qs[r][cc + 1] = bf2f(wq >> 16);
      ks[r][cc] = bf2f(wk & 0xffffu); ks[r][cc + 1] = bf2f(wk >> 16);
    }
    __syncthreads();
#pragma unroll 8
    for (int j = 0; j < 64; ++j) {
      float q0 = qs[ty * 2][j], q1 = qs[ty * 2 + 1][j];
      float k0 = ks[tx * 2][j], k1 = ks[tx * 2 + 1][j];
      a00 += q0 * k0; a01 += q0 * k1; a10 += q1 * k0; a11 += q1 * k1;
    }
    if (tid < 24) {
#pragma unroll 8
      for (int j = 0; j < 64; ++j) { float v = qs[tid][j]; sq += v * v; }
    } else if (tid < 48) {
#pragma unroll 8
      for (int j = 0; j < 64; ++j) { float v = ks[tid - 24][j]; sq += v * v; }
    }
  }
  const int c0 = ty * 2, d0 = tx * 2;
  if (c0 < 24 && d0 < 24) {
    atomicAdd(&Sb[h * 576 + c0 * 24 + d0], a00);
    atomicAdd(&Sb[h * 576 + c0 * 24 + d0 + 1], a01);
    atomicAdd(&Sb[h * 576 + (c0 + 1) * 24 + d0], a10);
    atomicAdd(&Sb[h * 576 + (c0 + 1) * 24 + d0 + 1], a11);
  }
  if (tid < 24) atomicAdd(&nqb[h * 24 + tid], sq);
  else if (tid < 48) atomicAdd(&nkb[h * 24 + tid - 24], sq);
}

// ---------------------------------------------------------------------------
// K4: attn = softmax(S*temp/(|q||k|)); Wcomb[o][h*24+d] = sum_c projW[o][h*24+c]*attn[c][d]
// ---------------------------------------------------------------------------
__global__ __launch_bounds__(256) void k_attn_wcomb(
    const float* __restrict__ Sb, const float* __restrict__ nqb,
    const float* __restrict__ nkb, const float* __restrict__ temp,
    const float* __restrict__ projw, float* __restrict__ wcomb)
{
  const int h = blockIdx.x;
  const int tid = threadIdx.x;
  __shared__ float attn[24][25];
  __shared__ float nqs[24], nks[24];
  if (tid < 24) nqs[tid] = fmaxf(sqrtf(nqb[h * 24 + tid]), 1e-12f);
  else if (tid < 48) nks[tid - 24] = fmaxf(sqrtf(nkb[h * 24 + tid - 24]), 1e-12f);
  __syncthreads();
  if (tid < 24) {
    const int c = tid;
    const float tmp = temp[h];
    float row[24];
    float m = -1e30f;
#pragma unroll
    for (int d = 0; d < 24; ++d) {
      float v = Sb[h * 576 + c * 24 + d] / (nqs[c] * nks[d]) * tmp;
      row[d] = v;
      m = fmaxf(m, v);
    }
    float ssum = 0.f;
#pragma unroll
    for (int d = 0; d < 24; ++d) { float e = __expf(row[d] - m); row[d] = e; ssum += e; }
    const float inv = 1.f / ssum;
#pragma unroll
    for (int d = 0; d < 24; ++d) attn[c][d] = row[d] * inv;
  }
  __syncthreads();
  for (int e = tid; e < 192 * 24; e += 256) {
    int o = e / 24, d = e % 24;
    float a = 0.f;
#pragma unroll
    for (int c = 0; c < 24; ++c) a += projw[o * 192 + h * 24 + c] * attn[c][d];
    wcomb[o * 192 + h * 24 + d] = a;
  }
}

// ---------------------------------------------------------------------------
extern "C" void kernel_launch(void* const* d_in, const int* in_sizes, int n_in,
                              void* d_out, int out_size, void* d_ws, size_t ws_size,
                              hipStream_t stream) {
  const float* x      = (const float*)d_in[0];
  const float* qkv_w  = (const float*)d_in[1];
  const float* qkv_b  = (const float*)d_in[2];
  const float* dw_w   = (const float*)d_in[3];
  const float* dw_b   = (const float*)d_in[4];
  const float* temp   = (const float*)d_in[5];
  const float* proj_w = (const float*)d_in[6];
  const float* proj_b = (const float*)d_in[7];
  float* out = (float*)d_out;

  char* ws = (char*)d_ws;
  size_t off = 0;
  unsigned short* post = (unsigned short*)(ws + off);
  off += (size_t)C3 * NTOK * sizeof(unsigned short);           // 37.75 MB
  float* Sb0  = (float*)(ws + off);                  // [2][8][576]
  float* nqb0 = Sb0 + 2 * HEADS * HD * HD;           // [2][8][24]
  float* nkb0 = nqb0 + 2 * HEADS * HD;               // [2][8][24]
  size_t stotal = (size_t)(2 * HEADS * HD * HD + 4 * HEADS * HD) * sizeof(float);
  off += stotal;
  float* wcomb = (float*)(ws + off); off += (size_t)CIN * CIN * sizeof(float);
  off = (off + 255) & ~(size_t)255;
  unsigned short* pre = (unsigned short*)(ws + off);

  size_t remain = (ws_size > off) ? ws_size - off : 0;
  int CH = (int)(remain / ((size_t)NTOK * sizeof(unsigned short)));
  if (CH > C3) CH = C3;
  CH = (CH / 64) * 64;
  if (CH < 64) CH = 64;   // below this we cannot fit; best effort

  hipMemsetAsync(Sb0, 0, stotal, stream);

  for (int b = 0; b < 2; ++b) {
    const float* xb = x + (size_t)b * CIN * NTOK;
    for (int cs = 0; cs < C3; cs += CH) {
      int cc = C3 - cs; if (cc > CH) cc = CH;
      dim3 g1(NTOK / 64, cc / 64);
      k_gemm_mfma<0, 0><<<g1, 256, 0, stream>>>(xb, qkv_w + (size_t)cs * CIN,
                                                qkv_b + cs, pre);
      dim3 g2(4, cc);
      k_dwconv<<<g2, 256, 0, stream>>>(pre, dw_w, dw_b, post, cs);
    }
    float* Sb  = Sb0 + (size_t)b * HEADS * HD * HD;
    float* nqb = nqb0 + (size_t)b * HEADS * HD;
    float* nkb = nkb0 + (size_t)b * HEADS * HD;
    dim3 g3(32, HEADS);
    k_gram<<<g3, 256, 0, stream>>>(post, Sb, nqb, nkb);
    k_attn_wcomb<<<HEADS, 256, 0, stream>>>(Sb, nqb, nkb, temp, proj_w, wcomb);
    dim3 g5(NTOK / 64, 3);
    k_gemm_mfma<1, 1><<<g5, 256, 0, stream>>>(post + (size_t)384 * NTOK, wcomb,
                                              proj_b, out + (size_t)b * CIN * NTOK);
  }
}

// Round 3
// 372.581 us; speedup vs baseline: 1.4986x; 1.0113x over previous
//
#include <hip/hip_runtime.h>

#define NTOK 32768   // 8*64*64 tokens
#define CIN 192
#define C3 576
#define HEADS 8
#define HD 24

typedef __attribute__((ext_vector_type(8))) short bf16x8;
typedef __attribute__((ext_vector_type(16))) float f32x16;

__device__ __forceinline__ float bf2f(unsigned int u) {
  union { unsigned int i; float f; } x; x.i = u << 16; return x.f;
}
__device__ __forceinline__ unsigned short f2bf(float f) {
  union { float f; unsigned int i; } x; x.f = f;
  unsigned int r = x.i + 0x7fffu + ((x.i >> 16) & 1u);
  return (unsigned short)(r >> 16);
}

// ---------------------------------------------------------------------------
// MFMA GEMM: Y[o,n] = bias[o] + sum_{c<192} W[o,c] * X[c,n]
// block 256 = 4 waves; tile 64(o) x 64(n); full K=192 staged once.
// 1D grid = 512*ot blocks, XCD-chunked swizzle: each XCD gets 64 consecutive
// n-tiles; within an XCD, o iterates fastest -> X panel L2-resident across ot.
// ---------------------------------------------------------------------------
template<int XBF, int OUTF32>
__global__ __launch_bounds__(256) void k_gemm_mfma(
    const void* __restrict__ Xv, const float* __restrict__ W,
    const float* __restrict__ bias, void* __restrict__ Yv, int ot)
{
  __shared__ __align__(16) unsigned short Wl[64][200];
  __shared__ __align__(16) unsigned short Xs[64][200];
  const int tid = threadIdx.x;
  const int bid = blockIdx.x;
  const int loc = bid >> 3;
  const int n0 = ((bid & 7) * 64 + loc / ot) * 64;   // NTOK/64/8 == 64 n-tiles/XCD
  const int o0 = (loc % ot) * 64;

  { // stage W (fp32 -> bf16): 64 rows x 192
    const int oo = tid >> 2;
    const int q0 = tid & 3;
#pragma unroll
    for (int j = 0; j < 12; ++j) {
      const int c = (j * 4 + q0) * 4;
      float4 v = *(const float4*)&W[(size_t)(o0 + oo) * CIN + c];
      Wl[oo][c]     = f2bf(v.x);
      Wl[oo][c + 1] = f2bf(v.y);
      Wl[oo][c + 2] = f2bf(v.z);
      Wl[oo][c + 3] = f2bf(v.w);
    }
  }
  { // stage X transposed -> Xs[n][c]
    const int nn = (tid & 31) * 2;
    const int cg = tid >> 5;           // 0..7
    if (XBF) {
      const unsigned short* X = (const unsigned short*)Xv;
#pragma unroll
      for (int j = 0; j < 24; ++j) {
        const int c = j * 8 + cg;
        unsigned int w = *(const unsigned int*)&X[(size_t)c * NTOK + n0 + nn];
        Xs[nn][c]     = (unsigned short)(w & 0xffffu);
        Xs[nn + 1][c] = (unsigned short)(w >> 16);
      }
    } else {
      const float* X = (const float*)Xv;
#pragma unroll
      for (int j = 0; j < 24; ++j) {
        const int c = j * 8 + cg;
        float2 v = *(const float2*)&X[(size_t)c * NTOK + n0 + nn];
        Xs[nn][c]     = f2bf(v.x);
        Xs[nn + 1][c] = f2bf(v.y);
      }
    }
  }
  __syncthreads();

  const int lane = tid & 63;
  const int wv = tid >> 6;
  const int o_w = (wv >> 1) * 32;
  const int n_w = (wv & 1) * 32;
  const int r32 = lane & 31;
  const int hi = lane >> 5;

  f32x16 acc;
#pragma unroll
  for (int i = 0; i < 16; ++i) acc[i] = 0.f;

  const unsigned short* wp = &Wl[o_w + r32][hi * 8];
  const unsigned short* xp = &Xs[n_w + r32][hi * 8];
#pragma unroll
  for (int kk = 0; kk < 12; ++kk) {
    bf16x8 a = *(const bf16x8*)(wp + kk * 16);
    bf16x8 b = *(const bf16x8*)(xp + kk * 16);
    acc = __builtin_amdgcn_mfma_f32_32x32x16_bf16(a, b, acc, 0, 0, 0);
  }
  __syncthreads();

  if (OUTF32) {
    float (*Yl)[68] = (float(*)[68])&Wl[0][0];   // 64*68*4 = 17408 B
#pragma unroll
    for (int r = 0; r < 16; ++r) {
      const int row = o_w + (r & 3) + 8 * (r >> 2) + 4 * hi;
      Yl[row][n_w + r32] = acc[r] + bias[o0 + row];
    }
    __syncthreads();
    float* Y = (float*)Yv;
    const int row = tid >> 2, seg = (tid & 3) * 16;
#pragma unroll
    for (int v = 0; v < 4; ++v) {
      float4 val = *(const float4*)&Yl[row][seg + v * 4];
      *(float4*)&Y[(size_t)(o0 + row) * NTOK + n0 + seg + v * 4] = val;
    }
  } else {
    unsigned short (*Yl)[72] = (unsigned short(*)[72])&Wl[0][0];  // 9216 B
#pragma unroll
    for (int r = 0; r < 16; ++r) {
      const int row = o_w + (r & 3) + 8 * (r >> 2) + 4 * hi;
      Yl[row][n_w + r32] = f2bf(acc[r] + bias[o0 + row]);
    }
    __syncthreads();
    unsigned short* Y = (unsigned short*)Yv;
    const int row = tid >> 2, seg = (tid & 3) * 16;
#pragma unroll
    for (int v = 0; v < 2; ++v) {
      bf16x8 val = *(const bf16x8*)&Yl[row][seg + v * 8];
      *(bf16x8*)&Y[(size_t)(o0 + row) * NTOK + n0 + seg + v * 8] = val;
    }
  }
}

// ---------------------------------------------------------------------------
// K2: depthwise 3x3x3, pad 1, bf16 in/out, fp32 math.
// Register sliding-window: per input t-plane, load 6x3 patch once (18 LDS
// reads) and scatter into all affected (t,hi) accumulators. 144 LDS reads
// per thread vs 864 in the naive form; FMA count unchanged (27/output).
// ---------------------------------------------------------------------------
__global__ __launch_bounds__(256) void k_dwconv(
    const unsigned short* __restrict__ in,   // [CH_chunk][8][64][64] bf16
    const float* __restrict__ wdw,           // [576][27]
    const float* __restrict__ bdw,           // [576]
    unsigned short* __restrict__ out,        // [576][8][64][64] bf16
    int c_start)
{
  const int tid = threadIdx.x;
  const int chl = blockIdx.y;
  const int ch = c_start + chl;
  const int h0 = blockIdx.x * 16;
  __shared__ float s[8][18][66];
  const unsigned short* inch = in + (size_t)chl * NTOK;

  for (int i = tid; i < 8 * 18 * 66; i += 256) {
    int t = i / (18 * 66);
    int rem = i % (18 * 66);
    int r = rem / 66;
    int cc = rem % 66;
    int h = h0 + r - 1;
    int w = cc - 1;
    float v = 0.f;
    if (h >= 0 && h < 64 && w >= 0 && w < 64)
      v = bf2f(inch[t * 4096 + h * 64 + w]);
    s[t][r][cc] = v;
  }
  float wr[27];
#pragma unroll
  for (int i = 0; i < 27; ++i) wr[i] = wdw[ch * 27 + i];
  const float bias = bdw[ch];
  __syncthreads();

  const int wloc = tid & 63;
  const int hl0 = (tid >> 6) * 4;   // one wave per hs group -> uniform rows
  float acc[8][4];
#pragma unroll
  for (int t = 0; t < 8; ++t)
#pragma unroll
    for (int i = 0; i < 4; ++i) acc[t][i] = 0.f;

#pragma unroll
  for (int tt = 0; tt < 8; ++tt) {
    float v[6][3];
#pragma unroll
    for (int r = 0; r < 6; ++r)
#pragma unroll
      for (int c = 0; c < 3; ++c)
        v[r][c] = s[tt][hl0 + r][wloc + c];
#pragma unroll
    for (int p = 0; p < 3; ++p) {     // weight t-plane
      const int t = tt + 1 - p;       // output t receiving this plane
      if (t < 0 || t > 7) continue;   // compile-time pruned
#pragma unroll
      for (int hi = 0; hi < 4; ++hi) {
        float a = 0.f;
#pragma unroll
        for (int dh = 0; dh < 3; ++dh)
#pragma unroll
          for (int dw = 0; dw < 3; ++dw)
            a += wr[p * 9 + dh * 3 + dw] * v[hi + dh][dw];
        acc[t][hi] += a;
      }
    }
  }

  unsigned short* outch = out + (size_t)ch * NTOK;
#pragma unroll
  for (int t = 0; t < 8; ++t)
#pragma unroll
    for (int hi = 0; hi < 4; ++hi)
      outch[t * 4096 + (h0 + hl0 + hi) * 64 + wloc] = f2bf(acc[t][hi] + bias);
}

// ---------------------------------------------------------------------------
// K3: Gram S[c,d] = sum_n q[c,n]k[d,n] + row sumsq, per head (bf16 input).
// ---------------------------------------------------------------------------
__global__ __launch_bounds__(256) void k_gram(
    const unsigned short* __restrict__ post,  // batch-local [576][NTOK] bf16
    float* __restrict__ Sb,                   // [8][24*24]
    float* __restrict__ nqb,                  // [8][24]
    float* __restrict__ nkb)                  // [8][24]
{
  const int tid = threadIdx.x;
  const int h = blockIdx.y;
  const int n0 = blockIdx.x * 1024;
  const unsigned short* q = post + (size_t)(h * HD) * NTOK;
  const unsigned short* k = post + (size_t)(192 + h * HD) * NTOK;
  __shared__ float qs[32][65];
  __shared__ float ks[32][65];

  for (int i = tid; i < 8 * 64; i += 256) {
    int r = 24 + (i >> 6);
    qs[r][i & 63] = 0.f;
    ks[r][i & 63] = 0.f;
  }

  const int ty = tid >> 4;
  const int tx = tid & 15;
  float a00 = 0, a01 = 0, a10 = 0, a11 = 0;
  float sq = 0;

  for (int sub = 0; sub < 16; ++sub) {
    __syncthreads();
    for (int i = tid; i < 768; i += 256) {
      int r = i >> 5, cc = (i & 31) * 2;
      int col = n0 + (sub << 6) + cc;
      unsigned int wq = *(const unsigned int*)&q[(size_t)r * NTOK + col];
      unsigned int wk = *(const unsigned int*)&k[(size_t)r * NTOK + col];
      qs[r][cc] = bf2f(wq & 0xffffu); qs[r][cc + 1] = bf2f(wq >> 16);
      ks[r][cc] = bf2f(wk & 0xffffu); ks[r][cc + 1] = bf2f(wk >> 16);
    }
    __syncthreads();
#pragma unroll 8
    for (int j = 0; j < 64; ++j) {
      float q0 = qs[ty * 2][j], q1 = qs[ty * 2 + 1][j];
      float k0 = ks[tx * 2][j], k1 = ks[tx * 2 + 1][j];
      a00 += q0 * k0; a01 += q0 * k1; a10 += q1 * k0; a11 += q1 * k1;
    }
    if (tid < 24) {
#pragma unroll 8
      for (int j = 0; j < 64; ++j) { float v = qs[tid][j]; sq += v * v; }
    } else if (tid < 48) {
#pragma unroll 8
      for (int j = 0; j < 64; ++j) { float v = ks[tid - 24][j]; sq += v * v; }
    }
  }
  const int c0 = ty * 2, d0 = tx * 2;
  if (c0 < 24 && d0 < 24) {
    atomicAdd(&Sb[h * 576 + c0 * 24 + d0], a00);
    atomicAdd(&Sb[h * 576 + c0 * 24 + d0 + 1], a01);
    atomicAdd(&Sb[h * 576 + (c0 + 1) * 24 + d0], a10);
    atomicAdd(&Sb[h * 576 + (c0 + 1) * 24 + d0 + 1], a11);
  }
  if (tid < 24) atomicAdd(&nqb[h * 24 + tid], sq);
  else if (tid < 48) atomicAdd(&nkb[h * 24 + tid - 24], sq);
}

// ---------------------------------------------------------------------------
// K4: attn = softmax(S*temp/(|q||k|)); Wcomb[o][h*24+d] = sum_c projW[o][h*24+c]*attn[c][d]
// ---------------------------------------------------------------------------
__global__ __launch_bounds__(256) void k_attn_wcomb(
    const float* __restrict__ Sb, const float* __restrict__ nqb,
    const float* __restrict__ nkb, const float* __restrict__ temp,
    const float* __restrict__ projw, float* __restrict__ wcomb)
{
  const int h = blockIdx.x;
  const int tid = threadIdx.x;
  __shared__ float attn[24][25];
  __shared__ float nqs[24], nks[24];
  if (tid < 24) nqs[tid] = fmaxf(sqrtf(nqb[h * 24 + tid]), 1e-12f);
  else if (tid < 48) nks[tid - 24] = fmaxf(sqrtf(nkb[h * 24 + tid - 24]), 1e-12f);
  __syncthreads();
  if (tid < 24) {
    const int c = tid;
    const float tmp = temp[h];
    float row[24];
    float m = -1e30f;
#pragma unroll
    for (int d = 0; d < 24; ++d) {
      float v = Sb[h * 576 + c * 24 + d] / (nqs[c] * nks[d]) * tmp;
      row[d] = v;
      m = fmaxf(m, v);
    }
    float ssum = 0.f;
#pragma unroll
    for (int d = 0; d < 24; ++d) { float e = __expf(row[d] - m); row[d] = e; ssum += e; }
    const float inv = 1.f / ssum;
#pragma unroll
    for (int d = 0; d < 24; ++d) attn[c][d] = row[d] * inv;
  }
  __syncthreads();
  for (int e = tid; e < 192 * 24; e += 256) {
    int o = e / 24, d = e % 24;
    float a = 0.f;
#pragma unroll
    for (int c = 0; c < 24; ++c) a += projw[o * 192 + h * 24 + c] * attn[c][d];
    wcomb[o * 192 + h * 24 + d] = a;
  }
}

// ---------------------------------------------------------------------------
extern "C" void kernel_launch(void* const* d_in, const int* in_sizes, int n_in,
                              void* d_out, int out_size, void* d_ws, size_t ws_size,
                              hipStream_t stream) {
  const float* x      = (const float*)d_in[0];
  const float* qkv_w  = (const float*)d_in[1];
  const float* qkv_b  = (const float*)d_in[2];
  const float* dw_w   = (const float*)d_in[3];
  const float* dw_b   = (const float*)d_in[4];
  const float* temp   = (const float*)d_in[5];
  const float* proj_w = (const float*)d_in[6];
  const float* proj_b = (const float*)d_in[7];
  float* out = (float*)d_out;

  char* ws = (char*)d_ws;
  size_t off = 0;
  unsigned short* post = (unsigned short*)(ws + off);
  off += (size_t)C3 * NTOK * sizeof(unsigned short);           // 37.75 MB
  float* Sb0  = (float*)(ws + off);                  // [2][8][576]
  float* nqb0 = Sb0 + 2 * HEADS * HD * HD;           // [2][8][24]
  float* nkb0 = nqb0 + 2 * HEADS * HD;               // [2][8][24]
  size_t stotal = (size_t)(2 * HEADS * HD * HD + 4 * HEADS * HD) * sizeof(float);
  off += stotal;
  float* wcomb = (float*)(ws + off); off += (size_t)CIN * CIN * sizeof(float);
  off = (off + 255) & ~(size_t)255;
  unsigned short* pre = (unsigned short*)(ws + off);

  size_t remain = (ws_size > off) ? ws_size - off : 0;
  int CH = (int)(remain / ((size_t)NTOK * sizeof(unsigned short)));
  if (CH > C3) CH = C3;
  CH = (CH / 64) * 64;
  if (CH < 64) CH = 64;   // below this we cannot fit; best effort

  hipMemsetAsync(Sb0, 0, stotal, stream);

  for (int b = 0; b < 2; ++b) {
    const float* xb = x + (size_t)b * CIN * NTOK;
    for (int cs = 0; cs < C3; cs += CH) {
      int cc = C3 - cs; if (cc > CH) cc = CH;
      int ot = cc / 64;
      dim3 g1((NTOK / 64) * ot);
      k_gemm_mfma<0, 0><<<g1, 256, 0, stream>>>(xb, qkv_w + (size_t)cs * CIN,
                                                qkv_b + cs, pre, ot);
      dim3 g2(4, cc);
      k_dwconv<<<g2, 256, 0, stream>>>(pre, dw_w, dw_b, post, cs);
    }
    float* Sb  = Sb0 + (size_t)b * HEADS * HD * HD;
    float* nqb = nqb0 + (size_t)b * HEADS * HD;
    float* nkb = nkb0 + (size_t)b * HEADS * HD;
    dim3 g3(32, HEADS);
    k_gram<<<g3, 256, 0, stream>>>(post, Sb, nqb, nkb);
    k_attn_wcomb<<<HEADS, 256, 0, stream>>>(Sb, nqb, nkb, temp, proj_w, wcomb);
    dim3 g5((NTOK / 64) * 3);
    k_gemm_mfma<1, 1><<<g5, 256, 0, stream>>>(post + (size_t)384 * NTOK, wcomb,
                                              proj_b, out + (size_t)b * CIN * NTOK, 3);
  }
}